// Round 22
// baseline (252.863 us; speedup 1.0000x reference)
//
#include <hip/hip_runtime.h>
#include <hip/hip_bf16.h>

// Transformer-XL relative MHA. S=1024, P=1024, B=4, E=1024, H=16, I=64, J=2048.
// R21: = R20 (best, 234.5us) + attn final-tile peel: for even-st blocks the
// last tile's upper 64 keys are provably all-masked (1088+64st > 1087+64st),
// so a half-body skips their staging/MFMA/exp/PV entirely. Numerics identical
// (skipped terms are p=0). Everything else byte-identical to R20.

typedef __bf16 bf16x8 __attribute__((ext_vector_type(8)));
typedef float f32x4 __attribute__((ext_vector_type(4)));

__device__ __forceinline__ unsigned short f2bf(float f) {
    unsigned int u = __float_as_uint(f);
    u = u + 0x7fffu + ((u >> 16) & 1u);   // RNE
    return (unsigned short)(u >> 16);
}
__device__ __forceinline__ float bf2f(unsigned short s) {
    return __uint_as_float((unsigned int)s << 16);
}
__device__ __forceinline__ bf16x8 ldfrag(const unsigned short* p) {
    uint4 u = *(const uint4*)p;
    return __builtin_bit_cast(bf16x8, u);
}
__device__ __forceinline__ bf16x8 ldfragb(const char* p) {
    uint4 u = *(const uint4*)p;
    return __builtin_bit_cast(bf16x8, u);
}
// Async global->LDS, 16B/lane. LDS dest = wave-uniform base + lane*16.
__device__ __forceinline__ void gl16(const void* g, void* l) {
    __builtin_amdgcn_global_load_lds(
        (const __attribute__((address_space(1))) void*)g,
        (__attribute__((address_space(3))) void*)l, 16, 0, 0);
}

// Single-launch fp32->bf16 cast for all 7 inputs (range dispatch).
__global__ __launch_bounds__(256)
void cast_all(const float* __restrict__ memory, const float* __restrict__ inputMHA,
              const float* __restrict__ posEmb, const float* __restrict__ W_kv,
              const float* __restrict__ W_q, const float* __restrict__ W_p,
              const float* __restrict__ W_out, unsigned short* __restrict__ Xh,
              unsigned short* __restrict__ Ph, unsigned short* __restrict__ Wkvh,
              unsigned short* __restrict__ Wqh, unsigned short* __restrict__ Wph,
              unsigned short* __restrict__ Woh)
{
    int bid = blockIdx.x;
    const float* src; unsigned short* dst; int base;
    if (bid < 4096)       { src = memory;   dst = Xh;            base = bid; }
    else if (bid < 8192)  { src = inputMHA; dst = Xh + 4194304;  base = bid - 4096; }
    else if (bid < 10240) { src = posEmb;   dst = Ph;            base = bid - 8192; }
    else if (bid < 12288) { src = W_kv;     dst = Wkvh;          base = bid - 10240; }
    else if (bid < 13312) { src = W_q;      dst = Wqh;           base = bid - 12288; }
    else if (bid < 14336) { src = W_p;      dst = Wph;           base = bid - 13312; }
    else                  { src = W_out;    dst = Woh;           base = bid - 14336; }
    size_t i = ((size_t)base * 256 + threadIdx.x) * 4;
    float4 f = *(const float4*)(src + i);
    uint2 pk;
    pk.x = f2bf(f.x) | ((unsigned int)f2bf(f.y) << 16);
    pk.y = f2bf(f.z) | ((unsigned int)f2bf(f.w) << 16);
    *(uint2*)(dst + i) = pk;
}

// ---------------------------------------------------------------------------
// Combined producer GEMM: kv (1024 blocks) + q (256) + pv (128), one launch.
// XCD-contiguous block swizzle (1408 = 8*176, bijective).
// ---------------------------------------------------------------------------
__global__ __launch_bounds__(256, 2)
void gemm_prod(const unsigned short* __restrict__ Xh, const unsigned short* __restrict__ Ph,
               const unsigned short* __restrict__ Wkvh, const unsigned short* __restrict__ Wqh,
               const unsigned short* __restrict__ Wph,
               const float* __restrict__ u, const float* __restrict__ v,
               unsigned short* __restrict__ Kh, unsigned short* __restrict__ VtH,
               unsigned short* __restrict__ quH, unsigned short* __restrict__ qvH,
               unsigned short* __restrict__ PvH)
{
    const int orig = blockIdx.x;
    const int bid = (orig & 7) * 176 + (orig >> 3);   // XCD-contiguous, bijective
    int mode, m0, n0;
    const unsigned short *A, *W;
    if (bid < 1024)      { mode = 0; A = Xh;           W = Wkvh; m0 = (bid >> 4) * 128;          n0 = (bid & 15) * 128; }
    else if (bid < 1280) { mode = 1; A = Xh + 4194304; W = Wqh;  m0 = ((bid - 1024) >> 3) * 128; n0 = ((bid - 1024) & 7) * 128; }
    else                 { mode = 2; A = Ph;           W = Wph;  m0 = ((bid - 1280) >> 3) * 128; n0 = ((bid - 1280) & 7) * 128; }

    __shared__ __align__(16) unsigned short As[128 * 64];
    __shared__ __align__(16) unsigned short Bs[128 * 64];
    const int tid = threadIdx.x;
    const int w = tid >> 6, lane = tid & 63;
    const int lg = lane >> 4, ln = lane & 15;
    const int wm = w >> 1, wn = w & 1;

    f32x4 acc[4][4];
    #pragma unroll
    for (int i = 0; i < 4; ++i)
        #pragma unroll
        for (int j = 0; j < 4; ++j) acc[i][j] = (f32x4){0.f, 0.f, 0.f, 0.f};

    const int rw = 8 * w + (lane >> 3);
    const int sslot = (lane & 7) ^ (lane >> 3);
    const int aoff = (ln & 7) << 4;

    for (int k0 = 0; k0 < 1024; k0 += 64) {
        __syncthreads();
        #pragma unroll
        for (int c = 0; c < 4; ++c) {
            int row = c * 32 + rw;
            gl16(A + (size_t)(m0 + row) * 1024 + k0 + sslot * 8,
                 (char*)As + (c * 32 + 8 * w) * 128);
            gl16(W + (size_t)(n0 + row) * 1024 + k0 + sslot * 8,
                 (char*)Bs + (c * 32 + 8 * w) * 128);
        }
        __syncthreads();
        #pragma unroll
        for (int kh = 0; kh < 2; ++kh) {
            bf16x8 af[4], bfr[4];
            #pragma unroll
            for (int f = 0; f < 4; ++f) {
                int ar = wm * 64 + f * 16 + ln;
                af[f] = *(const bf16x8*)((const char*)As + ar * 128 + ((((kh * 4 + lg) << 4) ^ aoff)));
                int br = wn * 64 + f * 16 + ln;
                bfr[f] = *(const bf16x8*)((const char*)Bs + br * 128 + ((((kh * 4 + lg) << 4) ^ aoff)));
            }
            #pragma unroll
            for (int i = 0; i < 4; ++i)
                #pragma unroll
                for (int j = 0; j < 4; ++j)
                    acc[i][j] = __builtin_amdgcn_mfma_f32_16x16x32_bf16(af[i], bfr[j], acc[i][j], 0, 0, 0);
        }
    }

    #pragma unroll
    for (int i = 0; i < 4; ++i) {
        #pragma unroll
        for (int r = 0; r < 4; ++r) {
            int m = m0 + wm * 64 + i * 16 + 4 * lg + r;
            #pragma unroll
            for (int j = 0; j < 4; ++j) {
                int n = n0 + wn * 64 + j * 16 + ln;
                float val = acc[i][j][r];
                if (mode == 0) {
                    int jrow = m >> 2, b = m & 3;
                    int isV = (n >= 1024);
                    int nn = n & 1023;
                    int h = nn >> 6, ii = nn & 63;
                    if (isV) {
                        VtH[((size_t)(b * 16 + h) * 64 + ii) * 2048 + jrow] = f2bf(val);
                    } else {
                        Kh[((size_t)(b * 16 + h) * 2048 + jrow) * 64 + ii] = f2bf(val);
                    }
                } else if (mode == 1) {
                    int s = m >> 2, bb = m & 3;
                    int h = n >> 6, ii = n & 63;
                    size_t base = ((size_t)(bb * 16 + h) * 1024 + s) * 64 + ii;
                    quH[base] = f2bf(val + u[n]);
                    qvH[base] = f2bf(val + v[n]);
                } else {
                    int h = n >> 6, ii = n & 63;
                    PvH[(size_t)h * 131072 + (size_t)m * 64 + ii] = f2bf(val);
                }
            }
        }
    }
}

// Out-GEMM: out = ctx @ W_out^T + residual (fp32 out). XCD-contiguous swizzle.
__global__ __launch_bounds__(256, 2)
void gemm_out(const unsigned short* __restrict__ A, const unsigned short* __restrict__ W,
              const float* __restrict__ resid, float* __restrict__ out)
{
    const int orig = blockIdx.x;
    const int bid = (orig & 7) * 32 + (orig >> 3);    // 256 = 8*32, bijective
    const int m0 = (bid >> 3) * 128, n0 = (bid & 7) * 128;

    __shared__ __align__(16) unsigned short As[128 * 64];
    __shared__ __align__(16) unsigned short Bs[128 * 64];
    const int tid = threadIdx.x;
    const int w = tid >> 6, lane = tid & 63;
    const int lg = lane >> 4, ln = lane & 15;
    const int wm = w >> 1, wn = w & 1;

    f32x4 acc[4][4];
    #pragma unroll
    for (int i = 0; i < 4; ++i)
        #pragma unroll
        for (int j = 0; j < 4; ++j) acc[i][j] = (f32x4){0.f, 0.f, 0.f, 0.f};

    const int rw = 8 * w + (lane >> 3);
    const int sslot = (lane & 7) ^ (lane >> 3);
    const int aoff = (ln & 7) << 4;

    for (int k0 = 0; k0 < 1024; k0 += 64) {
        __syncthreads();
        #pragma unroll
        for (int c = 0; c < 4; ++c) {
            int row = c * 32 + rw;
            gl16(A + (size_t)(m0 + row) * 1024 + k0 + sslot * 8,
                 (char*)As + (c * 32 + 8 * w) * 128);
            gl16(W + (size_t)(n0 + row) * 1024 + k0 + sslot * 8,
                 (char*)Bs + (c * 32 + 8 * w) * 128);
        }
        __syncthreads();
        #pragma unroll
        for (int kh = 0; kh < 2; ++kh) {
            bf16x8 af[4], bfr[4];
            #pragma unroll
            for (int f = 0; f < 4; ++f) {
                int ar = wm * 64 + f * 16 + ln;
                af[f] = *(const bf16x8*)((const char*)As + ar * 128 + ((((kh * 4 + lg) << 4) ^ aoff)));
                int br = wn * 64 + f * 16 + ln;
                bfr[f] = *(const bf16x8*)((const char*)Bs + br * 128 + ((((kh * 4 + lg) << 4) ^ aoff)));
            }
            #pragma unroll
            for (int i = 0; i < 4; ++i)
                #pragma unroll
                for (int j = 0; j < 4; ++j)
                    acc[i][j] = __builtin_amdgcn_mfma_f32_16x16x32_bf16(af[i], bfr[j], acc[i][j], 0, 0, 0);
        }
    }

    #pragma unroll
    for (int i = 0; i < 4; ++i) {
        #pragma unroll
        for (int r = 0; r < 4; ++r) {
            int m = m0 + wm * 64 + i * 16 + 4 * lg + r;
            #pragma unroll
            for (int j = 0; j < 4; ++j) {
                int n = n0 + wn * 64 + j * 16 + ln;
                out[(size_t)m * 1024 + n] = acc[i][j][r] + resid[(size_t)m * 1024 + n];
            }
        }
    }
}

// ---------------------------------------------------------------------------
// MFMA flash attention R21. Block = 64 q-rows, 4 waves, KVBLK=128 (R18 body)
// + final-tile peel: even-st blocks run a half-body on the last tile (upper
// 64 keys provably all-masked): K stage rows<64, Pv stage rows<128, QK fc<4,
// pos rc<5 (gather rr<=78 covered), exp/P fc<4, PV m<2. Garbage-row
// invariant g>=2048 <=> masked holds for the shortened window.
// ---------------------------------------------------------------------------
__global__ __launch_bounds__(256, 2)
void attn_mfma(const unsigned short* __restrict__ quG, const unsigned short* __restrict__ qvG,
               const unsigned short* __restrict__ Kg, const unsigned short* __restrict__ Pvg,
               const unsigned short* __restrict__ Vt, unsigned short* __restrict__ ctx)
{
    // XCD swizzle (bijective, 1024 % 8 == 0) + heavy-first st decode.
    const int orig = blockIdx.x;
    const int wg = (orig & 7) * 128 + (orig >> 3);
    const int st = 15 - (wg & 15), h = (wg >> 4) & 15, b = wg >> 8;
    const int s0 = st << 6;
    const int tid = threadIdx.x;
    const int w = tid >> 6, lane = tid & 63;
    const int lg = lane >> 4, ln = lane & 15;
    const int rowB = lg << 2;

    __shared__ __align__(16) unsigned short Ks[128 * 64];    // K tile (128B rows)
    __shared__ __align__(16) unsigned short Vts[64 * 128];   // Vt tile (256B rows)
    __shared__ __align__(16) unsigned short Pvs[192 * 64];   // Pv window (128B rows)
    __shared__ __align__(16) unsigned short WSs[4][2880];    // per-wave T(144x20)/P(16x128) overlay
    unsigned short* Tw = WSs[w];
    unsigned short* Pw = WSs[w];

    const size_t bh = (size_t)b * 16 + h;
    const unsigned short* quB = quG + bh * 65536;
    const unsigned short* qvB = qvG + bh * 65536;
    const unsigned short* kB  = Kg  + bh * 131072;
    const unsigned short* pvB = Pvg + (size_t)h * 131072;
    const unsigned short* vtB = Vt  + bh * 131072;

    const int q_abs = s0 + 16 * w + ln;
    bf16x8 quF[2], qvF[2];
    quF[0] = ldfrag(quB + (size_t)q_abs * 64 + 8 * lg);
    quF[1] = ldfrag(quB + (size_t)q_abs * 64 + 32 + 8 * lg);
    qvF[0] = ldfrag(qvB + (size_t)q_abs * 64 + 8 * lg);
    qvF[1] = ldfrag(qvB + (size_t)q_abs * 64 + 32 + 8 * lg);

    f32x4 accO[4];
    float l_acc[4];
    #pragma unroll
    for (int r = 0; r < 4; ++r) {
        l_acc[r] = 0.f;
        accO[r] = (f32x4){0.f, 0.f, 0.f, 0.f};
    }

    const int rw = 8 * w + (lane >> 3);           // 128B-row staging: row in 32-chunk
    const int sslot = (lane & 7) ^ (lane >> 3);   // swizzled global 16B slot (8/row)
    const int vrow = 4 * w + (lane >> 4);         // 256B-row staging: row in 16-chunk
    const int vslot = (lane & 15) ^ (vrow & 15);  // swizzled global 16B slot (16/row)
    const int wstart = 48 - 16 * w;               // wave's Pv-frag base in shared window
    const int nT = (18 + st) >> 1;
    const bool halfLast = ((st & 1) == 0);        // even st: last tile's upper 64 keys all-masked
    const int nFull = nT - (halfLast ? 1 : 0);
    const float ESC = 0.18033688f;                // 0.125 * log2(e)

    for (int t = 0; t < nFull; ++t) {
        const int j0 = t << 7;
        const int pvb = j0 + 960 - s0;            // shared window base (>= 0)

        __syncthreads();                          // prior phase done reading tiles
        #pragma unroll
        for (int c = 0; c < 4; ++c)               // stage K (128 rows; j <= 2047 always)
            gl16(kB + (size_t)(j0 + c * 32 + rw) * 64 + sslot * 8,
                 (char*)Ks + (c * 32 + 8 * w) * 128);
        #pragma unroll
        for (int c = 0; c < 4; ++c)               // stage Vt (64 rows x 256B)
            gl16(vtB + (size_t)(c * 16 + vrow) * 2048 + j0 + vslot * 8,
                 (char*)Vts + c * 4096 + w * 1024);
        #pragma unroll
        for (int c = 0; c < 6; ++c)               // stage Pv window (192 rows; OOB->masked)
            gl16(pvB + (size_t)(pvb + c * 32 + rw) * 64 + sslot * 8,
                 (char*)Pvs + (c * 32 + 8 * w) * 128);
        __syncthreads();

        __builtin_amdgcn_s_setprio(1);
        // ---- content scores from Ks (8 col-frags of 16 keys) ----
        f32x4 sC[8];
        #pragma unroll
        for (int fc = 0; fc < 8; ++fc) {
            int jl = ln + 16 * fc;
            const char* kb = (const char*)Ks + jl * 128;
            f32x4 z = {0.f, 0.f, 0.f, 0.f};
            z = __builtin_amdgcn_mfma_f32_16x16x32_bf16(quF[0], ldfragb(kb + ((lg ^ (jl & 7)) << 4)), z, 0, 0, 0);
            z = __builtin_amdgcn_mfma_f32_16x16x32_bf16(quF[1], ldfragb(kb + (((4 + lg) ^ (jl & 7)) << 4)), z, 0, 0, 0);
            sC[fc] = z;
        }

        // ---- pos-GEMM from Pvs -> per-wave transposed bf16 T (overlay) ----
        #pragma unroll
        for (int rc = 0; rc < 9; ++rc) {
            int wr = wstart + ln + 16 * rc;       // 0..191
            const char* pb = (const char*)Pvs + wr * 128;
            f32x4 z = {0.f, 0.f, 0.f, 0.f};
            z = __builtin_amdgcn_mfma_f32_16x16x32_bf16(qvF[0], ldfragb(pb + ((lg ^ (wr & 7)) << 4)), z, 0, 0, 0);
            z = __builtin_amdgcn_mfma_f32_16x16x32_bf16(qvF[1], ldfragb(pb + (((4 + lg) ^ (wr & 7)) << 4)), z, 0, 0, 0);
            uint2 pk;
            pk.x = f2bf(z[0]) | ((unsigned int)f2bf(z[1]) << 16);
            pk.y = f2bf(z[2]) | ((unsigned int)f2bf(z[3]) << 16);
            *(uint2*)&Tw[(ln + 16 * rc) * 20 + rowB] = pk;   // T[sr rowB..+3][wc]
        }
        __builtin_amdgcn_s_setprio(0);

        // ---- gather ALL shifted pos into regs (T fully read before P store) ----
        float sc[8][4];
        const bool anyMask = (j0 + 127 > 1024 + s0 + 16 * w);   // wave-uniform
        if (!anyMask) {
            #pragma unroll
            for (int fc = 0; fc < 8; ++fc) {
                int jc = ln + 16 * fc;
                #pragma unroll
                for (int r = 0; r < 4; ++r) {
                    int sr = rowB + r;
                    sc[fc][r] = (sC[fc][r] + bf2f(Tw[(jc - sr + 15) * 20 + sr])) * ESC;
                }
            }
        } else {
            #pragma unroll
            for (int fc = 0; fc < 8; ++fc) {
                int jc = ln + 16 * fc;
                int j_abs = j0 + jc;
                #pragma unroll
                for (int r = 0; r < 4; ++r) {
                    int sr = rowB + r;
                    float x = (sC[fc][r] + bf2f(Tw[(jc - sr + 15) * 20 + sr])) * ESC;
                    if (j_abs > 1024 + s0 + 16 * w + sr) x = -1e30f;   // exp2 -> 0
                    sc[fc][r] = x;
                }
            }
        }

        // ---- exp2 + P store (overlay region, T now dead; stride 128) ----
        #pragma unroll
        for (int fc = 0; fc < 8; ++fc) {
            int jc = ln + 16 * fc;
            #pragma unroll
            for (int r = 0; r < 4; ++r) {
                int sr = rowB + r;
                float p = __builtin_amdgcn_exp2f(sc[fc][r]);
                l_acc[r] += p;
                Pw[sr * 128 + (jc ^ ((sr & 7) << 3))] = f2bf(p);
            }
        }

        // ---- P A-frags (k=0..127 in 4 chunks) + PV from Vts ----
        __builtin_amdgcn_s_setprio(1);
        bf16x8 pa[4];
        #pragma unroll
        for (int m = 0; m < 4; ++m)
            pa[m] = ldfrag(&Pw[ln * 128 + ((32 * m + 8 * lg) ^ ((ln & 7) << 3))]);
        #pragma unroll
        for (int fc = 0; fc < 4; ++fc) {
            int il = ln + 16 * fc;
            const char* vb = (const char*)Vts + il * 256;
            #pragma unroll
            for (int m = 0; m < 4; ++m)
                accO[fc] = __builtin_amdgcn_mfma_f32_16x16x32_bf16(
                    pa[m], ldfragb(vb + (((4 * m + lg) ^ ln) << 4)), accO[fc], 0, 0, 0);
        }
        __builtin_amdgcn_s_setprio(0);
    }

    // ---- peeled half tile (even st): keys j0..j0+63 only ----
    if (halfLast) {
        const int j0 = (nT - 1) << 7;
        const int pvb = j0 + 960 - s0;

        __syncthreads();
        #pragma unroll
        for (int c = 0; c < 2; ++c)               // K rows 0..63 only (fc<4 reads jl<64)
            gl16(kB + (size_t)(j0 + c * 32 + rw) * 64 + sslot * 8,
                 (char*)Ks + (c * 32 + 8 * w) * 128);
        #pragma unroll
        for (int c = 0; c < 4; ++c)               // Vt full (only k<64 consumed)
            gl16(vtB + (size_t)(c * 16 + vrow) * 2048 + j0 + vslot * 8,
                 (char*)Vts + c * 4096 + w * 1024);
        #pragma unroll
        for (int c = 0; c < 4; ++c)               // Pv rows 0..127 (wr <= 127 needed)
            gl16(pvB + (size_t)(pvb + c * 32 + rw) * 64 + sslot * 8,
                 (char*)Pvs + (c * 32 + 8 * w) * 128);
        __syncthreads();

        __builtin_amdgcn_s_setprio(1);
        f32x4 sC[4];
        #pragma unroll
        for (int fc = 0; fc < 4; ++fc) {
            int jl = ln + 16 * fc;
            const char* kb = (const char*)Ks + jl * 128;
            f32x4 z = {0.f, 0.f, 0.f, 0.f};
            z = __builtin_amdgcn_mfma_f32_16x16x32_bf16(quF[0], ldfragb(kb + ((lg ^ (jl & 7)) << 4)), z, 0, 0, 0);
            z = __builtin_amdgcn_mfma_f32_16x16x32_bf16(quF[1], ldfragb(kb + (((4 + lg) ^ (jl & 7)) << 4)), z, 0, 0, 0);
            sC[fc] = z;
        }
        #pragma unroll
        for (int rc = 0; rc < 5; ++rc) {          // T cols 0..79 (gather uses rr<=78)
            int wr = wstart + ln + 16 * rc;
            const char* pb = (const char*)Pvs + wr * 128;
            f32x4 z = {0.f, 0.f, 0.f, 0.f};
            z = __builtin_amdgcn_mfma_f32_16x16x32_bf16(qvF[0], ldfragb(pb + ((lg ^ (wr & 7)) << 4)), z, 0, 0, 0);
            z = __builtin_amdgcn_mfma_f32_16x16x32_bf16(qvF[1], ldfragb(pb + (((4 + lg) ^ (wr & 7)) << 4)), z, 0, 0, 0);
            uint2 pk;
            pk.x = f2bf(z[0]) | ((unsigned int)f2bf(z[1]) << 16);
            pk.y = f2bf(z[2]) | ((unsigned int)f2bf(z[3]) << 16);
            *(uint2*)&Tw[(ln + 16 * rc) * 20 + rowB] = pk;
        }
        __builtin_amdgcn_s_setprio(0);

        float sc[4][4];
        #pragma unroll
        for (int fc = 0; fc < 4; ++fc) {
            int jc = ln + 16 * fc;
            int j_abs = j0 + jc;
            #pragma unroll
            for (int r = 0; r < 4; ++r) {
                int sr = rowB + r;
                float x = (sC[fc][r] + bf2f(Tw[(jc - sr + 15) * 20 + sr])) * ESC;
                if (j_abs > 1024 + s0 + 16 * w + sr) x = -1e30f;
                sc[fc][r] = x;
            }
        }
        #pragma unroll
        for (int fc = 0; fc < 4; ++fc) {
            int jc = ln + 16 * fc;
            #pragma unroll
            for (int r = 0; r < 4; ++r) {
                int sr = rowB + r;
                float p = __builtin_amdgcn_exp2f(sc[fc][r]);
                l_acc[r] += p;
                Pw[sr * 128 + (jc ^ ((sr & 7) << 3))] = f2bf(p);
            }
        }
        __builtin_amdgcn_s_setprio(1);
        bf16x8 pa[2];
        #pragma unroll
        for (int m = 0; m < 2; ++m)
            pa[m] = ldfrag(&Pw[ln * 128 + ((32 * m + 8 * lg) ^ ((ln & 7) << 3))]);
        #pragma unroll
        for (int fc = 0; fc < 4; ++fc) {          // all 4 output i-blocks
            int il = ln + 16 * fc;
            const char* vb = (const char*)Vts + il * 256;
            #pragma unroll
            for (int m = 0; m < 2; ++m)           // only keys 0..63
                accO[fc] = __builtin_amdgcn_mfma_f32_16x16x32_bf16(
                    pa[m], ldfragb(vb + (((4 * m + lg) ^ ln) << 4)), accO[fc], 0, 0, 0);
        }
        __builtin_amdgcn_s_setprio(0);
    }

    // ---- epilogue: reduce l once; normalize; store ----
    #pragma unroll
    for (int r = 0; r < 4; ++r) {
        float l = l_acc[r];
        l += __shfl_xor(l, 1, 64);
        l += __shfl_xor(l, 2, 64);
        l += __shfl_xor(l, 4, 64);
        l += __shfl_xor(l, 8, 64);
        float inv = 1.0f / l;
        #pragma unroll
        for (int fc = 0; fc < 4; ++fc) {
            size_t dst = ((size_t)(s0 + 16 * w + rowB + r) * 4 + b) * 1024 + h * 64 + ln + 16 * fc;
            ctx[dst] = f2bf(accO[fc][r] * inv);
        }
    }
}

// In-place LayerNorm over E=1024 per row.
__global__ __launch_bounds__(256)
void ln_kernel(float* __restrict__ io, const float* __restrict__ w, const float* __restrict__ bvec)
{
    int row = blockIdx.x;
    float* p = io + (size_t)row * 1024;
    int tid = threadIdx.x;
    float4 v = *(const float4*)(p + tid * 4);
    float s  = v.x + v.y + v.z + v.w;
    float s2 = v.x * v.x + v.y * v.y + v.z * v.z + v.w * v.w;
    #pragma unroll
    for (int off = 1; off < 64; off <<= 1) {
        s  += __shfl_xor(s,  off, 64);
        s2 += __shfl_xor(s2, off, 64);
    }
    __shared__ float red[8];
    int wv = tid >> 6;
    if ((tid & 63) == 0) { red[wv] = s; red[wv + 4] = s2; }
    __syncthreads();
    s  = red[0] + red[1] + red[2] + red[3];
    s2 = red[4] + red[5] + red[6] + red[7];
    float mu  = s * (1.0f / 1024.0f);
    float var = s2 * (1.0f / 1024.0f) - mu * mu;
    float rstd = rsqrtf(var + 1e-5f);
    float4 w4 = *(const float4*)(w + tid * 4);
    float4 b4 = *(const float4*)(bvec + tid * 4);
    float4 o;
    o.x = (v.x - mu) * rstd * w4.x + b4.x;
    o.y = (v.y - mu) * rstd * w4.y + b4.y;
    o.z = (v.z - mu) * rstd * w4.z + b4.z;
    o.w = (v.w - mu) * rstd * w4.w + b4.w;
    *(float4*)(p + tid * 4) = o;
}

extern "C" void kernel_launch(void* const* d_in, const int* in_sizes, int n_in,
                              void* d_out, int out_size, void* d_ws, size_t ws_size,
                              hipStream_t stream)
{
    const float* inputMHA = (const float*)d_in[0];
    const float* posEmb   = (const float*)d_in[1];
    const float* memory   = (const float*)d_in[2];
    const float* u        = (const float*)d_in[3];
    const float* v        = (const float*)d_in[4];
    const float* W_kv     = (const float*)d_in[5];
    const float* W_q      = (const float*)d_in[6];
    const float* W_p      = (const float*)d_in[7];
    const float* W_out    = (const float*)d_in[8];
    const float* ln_w     = (const float*)d_in[9];
    const float* ln_b     = (const float*)d_in[10];
    float* out = (float*)d_out;

    unsigned short* wsh  = (unsigned short*)d_ws;
    unsigned short* Kh   = wsh;                    // (B,H,J,I)  8388608
    unsigned short* VtH  = Kh   + 8388608;         // (B,H,I,J)  8388608
    unsigned short* quH  = VtH  + 8388608;         // (B,H,S,I)  4194304
    unsigned short* qvH  = quH  + 4194304;
    unsigned short* PvH  = qvH  + 4194304;         // (H,J,I)    2097152
    unsigned short* Xh   = PvH  + 2097152;         // (J,B,E)    8388608 (mem | input)
    unsigned short* Ph   = Xh   + 8388608;         // (J,E)      2097152
    unsigned short* Wkvh = Ph   + 2097152;         // 2097152
    unsigned short* Wqh  = Wkvh + 2097152;         // 1048576
    unsigned short* Wph  = Wqh  + 1048576;
    unsigned short* Woh  = Wph  + 1048576;
    unsigned short* ctxh = Woh  + 1048576;         // (S,B,E)    4194304
    if (ws_size < (size_t)94371840) return;        // ~90 MB

    cast_all<<<dim3(15360), 256, 0, stream>>>(memory, inputMHA, posEmb, W_kv, W_q, W_p, W_out,
                                              Xh, Ph, Wkvh, Wqh, Wph, Woh);
    gemm_prod<<<dim3(1408), 256, 0, stream>>>(Xh, Ph, Wkvh, Wqh, Wph, u, v,
                                              Kh, VtH, quH, qvH, PvH);
    attn_mfma<<<dim3(1024), 256, 0, stream>>>(quH, qvH, Kh, PvH, VtH, ctxh);
    gemm_out<<<dim3(256), 256, 0, stream>>>(ctxh, Woh, inputMHA, out);
    ln_kernel<<<dim3(4096), 256, 0, stream>>>(out, ln_w, ln_b);
}

// Round 23
// 233.738 us; speedup vs baseline: 1.0818x; 1.0818x over previous
//
#include <hip/hip_runtime.h>
#include <hip/hip_bf16.h>

// Transformer-XL relative MHA. S=1024, P=1024, B=4, E=1024, H=16, I=64, J=2048.
// R22: exact revert to R18/R20 (best, measured twice at 234.5-234.9 us).
// R21's tail-peel regressed (-18 us) via code-size/scheduling despite less
// work -- tail axis closed. This is the session's converged configuration:
// all-MFMA pipeline, gl16 staging w/ source-side swizzle, merged casts,
// merged producer GEMMs + T1 swizzles, no-max exp2 softmax, T/P overlay,
// wave-uniform mask-skip, setprio, heavy-first dispatch.

typedef __bf16 bf16x8 __attribute__((ext_vector_type(8)));
typedef float f32x4 __attribute__((ext_vector_type(4)));

__device__ __forceinline__ unsigned short f2bf(float f) {
    unsigned int u = __float_as_uint(f);
    u = u + 0x7fffu + ((u >> 16) & 1u);   // RNE
    return (unsigned short)(u >> 16);
}
__device__ __forceinline__ float bf2f(unsigned short s) {
    return __uint_as_float((unsigned int)s << 16);
}
__device__ __forceinline__ bf16x8 ldfrag(const unsigned short* p) {
    uint4 u = *(const uint4*)p;
    return __builtin_bit_cast(bf16x8, u);
}
__device__ __forceinline__ bf16x8 ldfragb(const char* p) {
    uint4 u = *(const uint4*)p;
    return __builtin_bit_cast(bf16x8, u);
}
// Async global->LDS, 16B/lane. LDS dest = wave-uniform base + lane*16.
__device__ __forceinline__ void gl16(const void* g, void* l) {
    __builtin_amdgcn_global_load_lds(
        (const __attribute__((address_space(1))) void*)g,
        (__attribute__((address_space(3))) void*)l, 16, 0, 0);
}

// Single-launch fp32->bf16 cast for all 7 inputs (range dispatch).
__global__ __launch_bounds__(256)
void cast_all(const float* __restrict__ memory, const float* __restrict__ inputMHA,
              const float* __restrict__ posEmb, const float* __restrict__ W_kv,
              const float* __restrict__ W_q, const float* __restrict__ W_p,
              const float* __restrict__ W_out, unsigned short* __restrict__ Xh,
              unsigned short* __restrict__ Ph, unsigned short* __restrict__ Wkvh,
              unsigned short* __restrict__ Wqh, unsigned short* __restrict__ Wph,
              unsigned short* __restrict__ Woh)
{
    int bid = blockIdx.x;
    const float* src; unsigned short* dst; int base;
    if (bid < 4096)       { src = memory;   dst = Xh;            base = bid; }
    else if (bid < 8192)  { src = inputMHA; dst = Xh + 4194304;  base = bid - 4096; }
    else if (bid < 10240) { src = posEmb;   dst = Ph;            base = bid - 8192; }
    else if (bid < 12288) { src = W_kv;     dst = Wkvh;          base = bid - 10240; }
    else if (bid < 13312) { src = W_q;      dst = Wqh;           base = bid - 12288; }
    else if (bid < 14336) { src = W_p;      dst = Wph;           base = bid - 13312; }
    else                  { src = W_out;    dst = Woh;           base = bid - 14336; }
    size_t i = ((size_t)base * 256 + threadIdx.x) * 4;
    float4 f = *(const float4*)(src + i);
    uint2 pk;
    pk.x = f2bf(f.x) | ((unsigned int)f2bf(f.y) << 16);
    pk.y = f2bf(f.z) | ((unsigned int)f2bf(f.w) << 16);
    *(uint2*)(dst + i) = pk;
}

// ---------------------------------------------------------------------------
// Combined producer GEMM: kv (1024 blocks) + q (256) + pv (128), one launch.
// XCD-contiguous block swizzle (1408 = 8*176, bijective).
// ---------------------------------------------------------------------------
__global__ __launch_bounds__(256, 2)
void gemm_prod(const unsigned short* __restrict__ Xh, const unsigned short* __restrict__ Ph,
               const unsigned short* __restrict__ Wkvh, const unsigned short* __restrict__ Wqh,
               const unsigned short* __restrict__ Wph,
               const float* __restrict__ u, const float* __restrict__ v,
               unsigned short* __restrict__ Kh, unsigned short* __restrict__ VtH,
               unsigned short* __restrict__ quH, unsigned short* __restrict__ qvH,
               unsigned short* __restrict__ PvH)
{
    const int orig = blockIdx.x;
    const int bid = (orig & 7) * 176 + (orig >> 3);   // XCD-contiguous, bijective
    int mode, m0, n0;
    const unsigned short *A, *W;
    if (bid < 1024)      { mode = 0; A = Xh;           W = Wkvh; m0 = (bid >> 4) * 128;          n0 = (bid & 15) * 128; }
    else if (bid < 1280) { mode = 1; A = Xh + 4194304; W = Wqh;  m0 = ((bid - 1024) >> 3) * 128; n0 = ((bid - 1024) & 7) * 128; }
    else                 { mode = 2; A = Ph;           W = Wph;  m0 = ((bid - 1280) >> 3) * 128; n0 = ((bid - 1280) & 7) * 128; }

    __shared__ __align__(16) unsigned short As[128 * 64];
    __shared__ __align__(16) unsigned short Bs[128 * 64];
    const int tid = threadIdx.x;
    const int w = tid >> 6, lane = tid & 63;
    const int lg = lane >> 4, ln = lane & 15;
    const int wm = w >> 1, wn = w & 1;

    f32x4 acc[4][4];
    #pragma unroll
    for (int i = 0; i < 4; ++i)
        #pragma unroll
        for (int j = 0; j < 4; ++j) acc[i][j] = (f32x4){0.f, 0.f, 0.f, 0.f};

    const int rw = 8 * w + (lane >> 3);
    const int sslot = (lane & 7) ^ (lane >> 3);
    const int aoff = (ln & 7) << 4;

    for (int k0 = 0; k0 < 1024; k0 += 64) {
        __syncthreads();
        #pragma unroll
        for (int c = 0; c < 4; ++c) {
            int row = c * 32 + rw;
            gl16(A + (size_t)(m0 + row) * 1024 + k0 + sslot * 8,
                 (char*)As + (c * 32 + 8 * w) * 128);
            gl16(W + (size_t)(n0 + row) * 1024 + k0 + sslot * 8,
                 (char*)Bs + (c * 32 + 8 * w) * 128);
        }
        __syncthreads();
        #pragma unroll
        for (int kh = 0; kh < 2; ++kh) {
            bf16x8 af[4], bfr[4];
            #pragma unroll
            for (int f = 0; f < 4; ++f) {
                int ar = wm * 64 + f * 16 + ln;
                af[f] = *(const bf16x8*)((const char*)As + ar * 128 + ((((kh * 4 + lg) << 4) ^ aoff)));
                int br = wn * 64 + f * 16 + ln;
                bfr[f] = *(const bf16x8*)((const char*)Bs + br * 128 + ((((kh * 4 + lg) << 4) ^ aoff)));
            }
            #pragma unroll
            for (int i = 0; i < 4; ++i)
                #pragma unroll
                for (int j = 0; j < 4; ++j)
                    acc[i][j] = __builtin_amdgcn_mfma_f32_16x16x32_bf16(af[i], bfr[j], acc[i][j], 0, 0, 0);
        }
    }

    #pragma unroll
    for (int i = 0; i < 4; ++i) {
        #pragma unroll
        for (int r = 0; r < 4; ++r) {
            int m = m0 + wm * 64 + i * 16 + 4 * lg + r;
            #pragma unroll
            for (int j = 0; j < 4; ++j) {
                int n = n0 + wn * 64 + j * 16 + ln;
                float val = acc[i][j][r];
                if (mode == 0) {
                    int jrow = m >> 2, b = m & 3;
                    int isV = (n >= 1024);
                    int nn = n & 1023;
                    int h = nn >> 6, ii = nn & 63;
                    if (isV) {
                        VtH[((size_t)(b * 16 + h) * 64 + ii) * 2048 + jrow] = f2bf(val);
                    } else {
                        Kh[((size_t)(b * 16 + h) * 2048 + jrow) * 64 + ii] = f2bf(val);
                    }
                } else if (mode == 1) {
                    int s = m >> 2, bb = m & 3;
                    int h = n >> 6, ii = n & 63;
                    size_t base = ((size_t)(bb * 16 + h) * 1024 + s) * 64 + ii;
                    quH[base] = f2bf(val + u[n]);
                    qvH[base] = f2bf(val + v[n]);
                } else {
                    int h = n >> 6, ii = n & 63;
                    PvH[(size_t)h * 131072 + (size_t)m * 64 + ii] = f2bf(val);
                }
            }
        }
    }
}

// Out-GEMM: out = ctx @ W_out^T + residual (fp32 out). XCD-contiguous swizzle.
__global__ __launch_bounds__(256, 2)
void gemm_out(const unsigned short* __restrict__ A, const unsigned short* __restrict__ W,
              const float* __restrict__ resid, float* __restrict__ out)
{
    const int orig = blockIdx.x;
    const int bid = (orig & 7) * 32 + (orig >> 3);    // 256 = 8*32, bijective
    const int m0 = (bid >> 3) * 128, n0 = (bid & 7) * 128;

    __shared__ __align__(16) unsigned short As[128 * 64];
    __shared__ __align__(16) unsigned short Bs[128 * 64];
    const int tid = threadIdx.x;
    const int w = tid >> 6, lane = tid & 63;
    const int lg = lane >> 4, ln = lane & 15;
    const int wm = w >> 1, wn = w & 1;

    f32x4 acc[4][4];
    #pragma unroll
    for (int i = 0; i < 4; ++i)
        #pragma unroll
        for (int j = 0; j < 4; ++j) acc[i][j] = (f32x4){0.f, 0.f, 0.f, 0.f};

    const int rw = 8 * w + (lane >> 3);
    const int sslot = (lane & 7) ^ (lane >> 3);
    const int aoff = (ln & 7) << 4;

    for (int k0 = 0; k0 < 1024; k0 += 64) {
        __syncthreads();
        #pragma unroll
        for (int c = 0; c < 4; ++c) {
            int row = c * 32 + rw;
            gl16(A + (size_t)(m0 + row) * 1024 + k0 + sslot * 8,
                 (char*)As + (c * 32 + 8 * w) * 128);
            gl16(W + (size_t)(n0 + row) * 1024 + k0 + sslot * 8,
                 (char*)Bs + (c * 32 + 8 * w) * 128);
        }
        __syncthreads();
        #pragma unroll
        for (int kh = 0; kh < 2; ++kh) {
            bf16x8 af[4], bfr[4];
            #pragma unroll
            for (int f = 0; f < 4; ++f) {
                int ar = wm * 64 + f * 16 + ln;
                af[f] = *(const bf16x8*)((const char*)As + ar * 128 + ((((kh * 4 + lg) << 4) ^ aoff)));
                int br = wn * 64 + f * 16 + ln;
                bfr[f] = *(const bf16x8*)((const char*)Bs + br * 128 + ((((kh * 4 + lg) << 4) ^ aoff)));
            }
            #pragma unroll
            for (int i = 0; i < 4; ++i)
                #pragma unroll
                for (int j = 0; j < 4; ++j)
                    acc[i][j] = __builtin_amdgcn_mfma_f32_16x16x32_bf16(af[i], bfr[j], acc[i][j], 0, 0, 0);
        }
    }

    #pragma unroll
    for (int i = 0; i < 4; ++i) {
        #pragma unroll
        for (int r = 0; r < 4; ++r) {
            int m = m0 + wm * 64 + i * 16 + 4 * lg + r;
            #pragma unroll
            for (int j = 0; j < 4; ++j) {
                int n = n0 + wn * 64 + j * 16 + ln;
                out[(size_t)m * 1024 + n] = acc[i][j][r] + resid[(size_t)m * 1024 + n];
            }
        }
    }
}

// ---------------------------------------------------------------------------
// MFMA flash attention (R18 exact). Block = 64 q-rows, 4 waves, KVBLK=128.
// gl16 staging; per-wave T/P overlay; wave-uniform mask-skip; folded exp2;
// deferred normalization; s_setprio around MFMA clusters; heavy-first st.
// ---------------------------------------------------------------------------
__global__ __launch_bounds__(256, 2)
void attn_mfma(const unsigned short* __restrict__ quG, const unsigned short* __restrict__ qvG,
               const unsigned short* __restrict__ Kg, const unsigned short* __restrict__ Pvg,
               const unsigned short* __restrict__ Vt, unsigned short* __restrict__ ctx)
{
    // XCD swizzle (bijective, 1024 % 8 == 0) + heavy-first st decode.
    const int orig = blockIdx.x;
    const int wg = (orig & 7) * 128 + (orig >> 3);
    const int st = 15 - (wg & 15), h = (wg >> 4) & 15, b = wg >> 8;
    const int s0 = st << 6;
    const int tid = threadIdx.x;
    const int w = tid >> 6, lane = tid & 63;
    const int lg = lane >> 4, ln = lane & 15;
    const int rowB = lg << 2;

    __shared__ __align__(16) unsigned short Ks[128 * 64];    // K tile (128B rows)
    __shared__ __align__(16) unsigned short Vts[64 * 128];   // Vt tile (256B rows)
    __shared__ __align__(16) unsigned short Pvs[192 * 64];   // Pv window (128B rows)
    __shared__ __align__(16) unsigned short WSs[4][2880];    // per-wave T(144x20)/P(16x128) overlay
    unsigned short* Tw = WSs[w];
    unsigned short* Pw = WSs[w];

    const size_t bh = (size_t)b * 16 + h;
    const unsigned short* quB = quG + bh * 65536;
    const unsigned short* qvB = qvG + bh * 65536;
    const unsigned short* kB  = Kg  + bh * 131072;
    const unsigned short* pvB = Pvg + (size_t)h * 131072;
    const unsigned short* vtB = Vt  + bh * 131072;

    const int q_abs = s0 + 16 * w + ln;
    bf16x8 quF[2], qvF[2];
    quF[0] = ldfrag(quB + (size_t)q_abs * 64 + 8 * lg);
    quF[1] = ldfrag(quB + (size_t)q_abs * 64 + 32 + 8 * lg);
    qvF[0] = ldfrag(qvB + (size_t)q_abs * 64 + 8 * lg);
    qvF[1] = ldfrag(qvB + (size_t)q_abs * 64 + 32 + 8 * lg);

    f32x4 accO[4];
    float l_acc[4];
    #pragma unroll
    for (int r = 0; r < 4; ++r) {
        l_acc[r] = 0.f;
        accO[r] = (f32x4){0.f, 0.f, 0.f, 0.f};
    }

    const int rw = 8 * w + (lane >> 3);           // 128B-row staging: row in 32-chunk
    const int sslot = (lane & 7) ^ (lane >> 3);   // swizzled global 16B slot (8/row)
    const int vrow = 4 * w + (lane >> 4);         // 256B-row staging: row in 16-chunk
    const int vslot = (lane & 15) ^ (vrow & 15);  // swizzled global 16B slot (16/row)
    const int wstart = 48 - 16 * w;               // wave's Pv-frag base in shared window
    const int nT = (18 + st) >> 1;
    const float ESC = 0.18033688f;                // 0.125 * log2(e)

    for (int t = 0; t < nT; ++t) {
        const int j0 = t << 7;
        const int pvb = j0 + 960 - s0;            // shared window base (>= 0)

        __syncthreads();                          // prior phase done reading tiles
        #pragma unroll
        for (int c = 0; c < 4; ++c)               // stage K (128 rows; j <= 2047 always)
            gl16(kB + (size_t)(j0 + c * 32 + rw) * 64 + sslot * 8,
                 (char*)Ks + (c * 32 + 8 * w) * 128);
        #pragma unroll
        for (int c = 0; c < 4; ++c)               // stage Vt (64 rows x 256B)
            gl16(vtB + (size_t)(c * 16 + vrow) * 2048 + j0 + vslot * 8,
                 (char*)Vts + c * 4096 + w * 1024);
        #pragma unroll
        for (int c = 0; c < 6; ++c)               // stage Pv window (192 rows; OOB->masked)
            gl16(pvB + (size_t)(pvb + c * 32 + rw) * 64 + sslot * 8,
                 (char*)Pvs + (c * 32 + 8 * w) * 128);
        __syncthreads();

        __builtin_amdgcn_s_setprio(1);
        // ---- content scores from Ks (8 col-frags of 16 keys) ----
        f32x4 sC[8];
        #pragma unroll
        for (int fc = 0; fc < 8; ++fc) {
            int jl = ln + 16 * fc;
            const char* kb = (const char*)Ks + jl * 128;
            f32x4 z = {0.f, 0.f, 0.f, 0.f};
            z = __builtin_amdgcn_mfma_f32_16x16x32_bf16(quF[0], ldfragb(kb + ((lg ^ (jl & 7)) << 4)), z, 0, 0, 0);
            z = __builtin_amdgcn_mfma_f32_16x16x32_bf16(quF[1], ldfragb(kb + (((4 + lg) ^ (jl & 7)) << 4)), z, 0, 0, 0);
            sC[fc] = z;
        }

        // ---- pos-GEMM from Pvs -> per-wave transposed bf16 T (overlay) ----
        #pragma unroll
        for (int rc = 0; rc < 9; ++rc) {
            int wr = wstart + ln + 16 * rc;       // 0..191
            const char* pb = (const char*)Pvs + wr * 128;
            f32x4 z = {0.f, 0.f, 0.f, 0.f};
            z = __builtin_amdgcn_mfma_f32_16x16x32_bf16(qvF[0], ldfragb(pb + ((lg ^ (wr & 7)) << 4)), z, 0, 0, 0);
            z = __builtin_amdgcn_mfma_f32_16x16x32_bf16(qvF[1], ldfragb(pb + (((4 + lg) ^ (wr & 7)) << 4)), z, 0, 0, 0);
            uint2 pk;
            pk.x = f2bf(z[0]) | ((unsigned int)f2bf(z[1]) << 16);
            pk.y = f2bf(z[2]) | ((unsigned int)f2bf(z[3]) << 16);
            *(uint2*)&Tw[(ln + 16 * rc) * 20 + rowB] = pk;   // T[sr rowB..+3][wc]
        }
        __builtin_amdgcn_s_setprio(0);

        // ---- gather ALL shifted pos into regs (T fully read before P store) ----
        float sc[8][4];
        const bool anyMask = (j0 + 127 > 1024 + s0 + 16 * w);   // wave-uniform
        if (!anyMask) {
            #pragma unroll
            for (int fc = 0; fc < 8; ++fc) {
                int jc = ln + 16 * fc;
                #pragma unroll
                for (int r = 0; r < 4; ++r) {
                    int sr = rowB + r;
                    sc[fc][r] = (sC[fc][r] + bf2f(Tw[(jc - sr + 15) * 20 + sr])) * ESC;
                }
            }
        } else {
            #pragma unroll
            for (int fc = 0; fc < 8; ++fc) {
                int jc = ln + 16 * fc;
                int j_abs = j0 + jc;
                #pragma unroll
                for (int r = 0; r < 4; ++r) {
                    int sr = rowB + r;
                    float x = (sC[fc][r] + bf2f(Tw[(jc - sr + 15) * 20 + sr])) * ESC;
                    if (j_abs > 1024 + s0 + 16 * w + sr) x = -1e30f;   // exp2 -> 0
                    sc[fc][r] = x;
                }
            }
        }

        // ---- exp2 + P store (overlay region, T now dead; stride 128) ----
        #pragma unroll
        for (int fc = 0; fc < 8; ++fc) {
            int jc = ln + 16 * fc;
            #pragma unroll
            for (int r = 0; r < 4; ++r) {
                int sr = rowB + r;
                float p = __builtin_amdgcn_exp2f(sc[fc][r]);
                l_acc[r] += p;
                Pw[sr * 128 + (jc ^ ((sr & 7) << 3))] = f2bf(p);
            }
        }

        // ---- P A-frags (k=0..127 in 4 chunks) + PV from Vts ----
        __builtin_amdgcn_s_setprio(1);
        bf16x8 pa[4];
        #pragma unroll
        for (int m = 0; m < 4; ++m)
            pa[m] = ldfrag(&Pw[ln * 128 + ((32 * m + 8 * lg) ^ ((ln & 7) << 3))]);
        #pragma unroll
        for (int fc = 0; fc < 4; ++fc) {
            int il = ln + 16 * fc;
            const char* vb = (const char*)Vts + il * 256;
            #pragma unroll
            for (int m = 0; m < 4; ++m)
                accO[fc] = __builtin_amdgcn_mfma_f32_16x16x32_bf16(
                    pa[m], ldfragb(vb + (((4 * m + lg) ^ ln) << 4)), accO[fc], 0, 0, 0);
        }
        __builtin_amdgcn_s_setprio(0);
    }

    // ---- epilogue: reduce l once; normalize; store ----
    #pragma unroll
    for (int r = 0; r < 4; ++r) {
        float l = l_acc[r];
        l += __shfl_xor(l, 1, 64);
        l += __shfl_xor(l, 2, 64);
        l += __shfl_xor(l, 4, 64);
        l += __shfl_xor(l, 8, 64);
        float inv = 1.0f / l;
        #pragma unroll
        for (int fc = 0; fc < 4; ++fc) {
            size_t dst = ((size_t)(s0 + 16 * w + rowB + r) * 4 + b) * 1024 + h * 64 + ln + 16 * fc;
            ctx[dst] = f2bf(accO[fc][r] * inv);
        }
    }
}

// In-place LayerNorm over E=1024 per row.
__global__ __launch_bounds__(256)
void ln_kernel(float* __restrict__ io, const float* __restrict__ w, const float* __restrict__ bvec)
{
    int row = blockIdx.x;
    float* p = io + (size_t)row * 1024;
    int tid = threadIdx.x;
    float4 v = *(const float4*)(p + tid * 4);
    float s  = v.x + v.y + v.z + v.w;
    float s2 = v.x * v.x + v.y * v.y + v.z * v.z + v.w * v.w;
    #pragma unroll
    for (int off = 1; off < 64; off <<= 1) {
        s  += __shfl_xor(s,  off, 64);
        s2 += __shfl_xor(s2, off, 64);
    }
    __shared__ float red[8];
    int wv = tid >> 6;
    if ((tid & 63) == 0) { red[wv] = s; red[wv + 4] = s2; }
    __syncthreads();
    s  = red[0] + red[1] + red[2] + red[3];
    s2 = red[4] + red[5] + red[6] + red[7];
    float mu  = s * (1.0f / 1024.0f);
    float var = s2 * (1.0f / 1024.0f) - mu * mu;
    float rstd = rsqrtf(var + 1e-5f);
    float4 w4 = *(const float4*)(w + tid * 4);
    float4 b4 = *(const float4*)(bvec + tid * 4);
    float4 o;
    o.x = (v.x - mu) * rstd * w4.x + b4.x;
    o.y = (v.y - mu) * rstd * w4.y + b4.y;
    o.z = (v.z - mu) * rstd * w4.z + b4.z;
    o.w = (v.w - mu) * rstd * w4.w + b4.w;
    *(float4*)(p + tid * 4) = o;
}

extern "C" void kernel_launch(void* const* d_in, const int* in_sizes, int n_in,
                              void* d_out, int out_size, void* d_ws, size_t ws_size,
                              hipStream_t stream)
{
    const float* inputMHA = (const float*)d_in[0];
    const float* posEmb   = (const float*)d_in[1];
    const float* memory   = (const float*)d_in[2];
    const float* u        = (const float*)d_in[3];
    const float* v        = (const float*)d_in[4];
    const float* W_kv     = (const float*)d_in[5];
    const float* W_q      = (const float*)d_in[6];
    const float* W_p      = (const float*)d_in[7];
    const float* W_out    = (const float*)d_in[8];
    const float* ln_w     = (const float*)d_in[9];
    const float* ln_b     = (const float*)d_in[10];
    float* out = (float*)d_out;

    unsigned short* wsh  = (unsigned short*)d_ws;
    unsigned short* Kh   = wsh;                    // (B,H,J,I)  8388608
    unsigned short* VtH  = Kh   + 8388608;         // (B,H,I,J)  8388608
    unsigned short* quH  = VtH  + 8388608;         // (B,H,S,I)  4194304
    unsigned short* qvH  = quH  + 4194304;
    unsigned short* PvH  = qvH  + 4194304;         // (H,J,I)    2097152
    unsigned short* Xh   = PvH  + 2097152;         // (J,B,E)    8388608 (mem | input)
    unsigned short* Ph   = Xh   + 8388608;         // (J,E)      2097152
    unsigned short* Wkvh = Ph   + 2097152;         // 2097152
    unsigned short* Wqh  = Wkvh + 2097152;         // 1048576
    unsigned short* Wph  = Wqh  + 1048576;
    unsigned short* Woh  = Wph  + 1048576;
    unsigned short* ctxh = Woh  + 1048576;         // (S,B,E)    4194304
    if (ws_size < (size_t)94371840) return;        // ~90 MB

    cast_all<<<dim3(15360), 256, 0, stream>>>(memory, inputMHA, posEmb, W_kv, W_q, W_p, W_out,
                                              Xh, Ph, Wkvh, Wqh, Wph, Woh);
    gemm_prod<<<dim3(1408), 256, 0, stream>>>(Xh, Ph, Wkvh, Wqh, Wph, u, v,
                                              Kh, VtH, quH, qvH, PvH);
    attn_mfma<<<dim3(1024), 256, 0, stream>>>(quH, qvH, Kh, PvH, VtH, ctxh);
    gemm_out<<<dim3(256), 256, 0, stream>>>(ctxh, Woh, inputMHA, out);
    ln_kernel<<<dim3(4096), 256, 0, stream>>>(out, ln_w, ln_b);
}